// Round 10
// baseline (771.928 us; speedup 1.0000x reference)
//
#include <hip/hip_runtime.h>
#include <hip/hip_bf16.h>
#include <stdint.h>

#define N_TOK 2048
#define DM    2048
#define NEXP  64
#define TOPK  4
#define HEXP  512
#define CAPC  512
#define NSH   2
#define HSH   2048
#define RTB   8

typedef __attribute__((ext_vector_type(8))) short short8;
typedef __attribute__((ext_vector_type(4))) float f32x4;
typedef __attribute__((ext_vector_type(4))) float f4;
typedef __attribute__((ext_vector_type(4))) unsigned uint4v;

#define GLDS16(g, l) __builtin_amdgcn_global_load_lds(                     \
    (const __attribute__((address_space(1))) void*)(g),                    \
    (__attribute__((address_space(3))) void*)(l), 16, 0, 0)

#define VMWAIT(N) asm volatile("s_waitcnt vmcnt(" #N ")" ::: "memory")
#define BARX() do { asm volatile("" ::: "memory");                          \
                    __builtin_amdgcn_s_barrier();                           \
                    asm volatile("" ::: "memory"); } while (0)

static __device__ __forceinline__ unsigned short f2bf(float f) {
  union { float f; unsigned u; } v; v.f = f;
  unsigned r = v.u + 0x7FFFu + ((v.u >> 16) & 1u);   // RNE
  return (unsigned short)(r >> 16);
}

static __device__ __forceinline__ unsigned pk2(float lo, float hi) {
  unsigned u;
  asm("v_cvt_pk_bf16_f32 %0, %1, %2" : "=v"(u) : "v"(lo), "v"(hi));
  return u;
}

// ---------------------------------------------------------------- convert x
__global__ __launch_bounds__(256) void k_convert(const float* __restrict__ x,
                                                 unsigned short* __restrict__ xb) {
  int i = (blockIdx.x * 256 + threadIdx.x) * 8;
  f4 a = *(const f4*)(x + i);
  f4 b = *(const f4*)(x + i + 4);
  short8 o;
  o[0]=f2bf(a[0]); o[1]=f2bf(a[1]); o[2]=f2bf(a[2]); o[3]=f2bf(a[3]);
  o[4]=f2bf(b[0]); o[5]=f2bf(b[1]); o[6]=f2bf(b[2]); o[7]=f2bf(b[3]);
  *(short8*)(xb + i) = o;
}

// ---------------------------------------------------------------- router
#define ARGMAX_ROUND(S,I)                                            \
  { float bv = v; int bi = lane;                                     \
    _Pragma("unroll")                                                \
    for (int o = 32; o; o >>= 1) {                                   \
      float ov = __shfl_xor(bv, o); int oi = __shfl_xor(bi, o);      \
      if (ov > bv || (ov == bv && oi < bi)) { bv = ov; bi = oi; }    \
    }                                                                \
    S = bv; I = bi; if (lane == bi) v = -1.f; }

__global__ __launch_bounds__(256) void k_router(const float* __restrict__ x,
    const float* __restrict__ Wr, const float* __restrict__ bias,
    int* __restrict__ cnt, int* __restrict__ lists, float* __restrict__ wlist) {
  __shared__ float part[4][RTB][64];
  __shared__ float logits[RTB][64];
  int t = threadIdx.x;
  int e = t & 63, sl = t >> 6;
  int tok0 = blockIdx.x * RTB;
  const float* xp = x + (size_t)tok0 * DM;
  float acc[RTB];
#pragma unroll
  for (int i = 0; i < RTB; ++i) acc[i] = 0.f;
  for (int d = sl * 512; d < sl * 512 + 512; ++d) {
    float w = Wr[(size_t)d * NEXP + e];
#pragma unroll
    for (int i = 0; i < RTB; ++i) acc[i] += xp[(size_t)i * DM + d] * w;
  }
#pragma unroll
  for (int i = 0; i < RTB; ++i) part[sl][i][e] = acc[i];
  __syncthreads();
  for (int i = sl; i < RTB; i += 4)
    logits[i][e] = part[0][i][e] + part[1][i][e] + part[2][i][e] + part[3][i][e] + bias[e];
  __syncthreads();
  int lane = t & 63, wv = t >> 6;
  for (int i = wv * 2; i < wv * 2 + 2; ++i) {
    float lg = logits[i][lane];
    float m = lg;
#pragma unroll
    for (int o = 32; o; o >>= 1) m = fmaxf(m, __shfl_xor(m, o));
    float p = expf(lg - m);
    float sm = p;
#pragma unroll
    for (int o = 32; o; o >>= 1) sm += __shfl_xor(sm, o);
    float v = p / sm;
    float s0, s1, s2, s3; int i0, i1, i2, i3;
    ARGMAX_ROUND(s0, i0)
    ARGMAX_ROUND(s1, i1)
    ARGMAX_ROUND(s2, i2)
    ARGMAX_ROUND(s3, i3)
    float tot = s0 + s1 + s2 + s3;
    if (lane < TOPK) {
      float myw = (lane == 0 ? s0 : lane == 1 ? s1 : lane == 2 ? s2 : s3) / tot;
      int   mye = (lane == 0 ? i0 : lane == 1 ? i1 : lane == 2 ? i2 : i3);
      int pos = atomicAdd(&cnt[mye], 1);
      if (pos < CAPC) {
        lists[mye * CAPC + pos] = tok0 + i;
        wlist[mye * CAPC + pos] = myw;
      }
    }
  }
}

// ---------------------------------------------------------------- offsets
__global__ void k_offs(const int* __restrict__ cnt, int* __restrict__ offs) {
  int l = threadIdx.x;
  int c = min(cnt[l], CAPC);
  int sum = c;
#pragma unroll
  for (int o = 1; o < 64; o <<= 1) {
    int ov = __shfl_up(sum, o);
    if (l >= o) sum += ov;
  }
  offs[l + 1] = sum;
  if (l == 0) offs[0] = 0;
}

// ---------------------------------------------------------------- common frag helpers
static __device__ __forceinline__ short8 frag_ldA(const unsigned short* lds, int row, int kElem) {
  int byte = row * 64 + kElem * 2;
  byte ^= ((row >> 1) & 3) << 4;
  return *(const short8*)((const char*)lds + byte);
}

static __device__ __forceinline__ float silu_mul(float g, float u) {
  return g / (1.f + expf(-g)) * u;
}

#define A_SETUP(asrc, SROW_EXPR)                                            \
  const unsigned short* asrc[2];                                            \
  {                                                                         \
    _Pragma("unroll")                                                       \
    for (int p = 0; p < 2; ++p) {                                           \
      int row = p * 64 + wv * 16 + (lane >> 2);                             \
      int srow = (SROW_EXPR);                                               \
      asrc[p] = Abase + (size_t)srow * lda                                  \
              + (((lane & 3) ^ ((row >> 1) & 3)) << 3);                     \
    }                                                                       \
  }
#define A_STAGE(asrc, lAbuf, k0)                                            \
  { _Pragma("unroll")                                                       \
    for (int p = 0; p < 2; ++p)                                             \
      GLDS16(asrc[p] + (k0), (lAbuf) + p * 2048 + wv * 512); }

// ================================================================ BLOCKED-BF16 PATH
// Blob layout per (matrix m, n-block nb of 64 cols):
//   u32 element idx = ((nbG*K2 + k2)*64 + slot), nbG = m*(N/64)+nb, K2 = K/2
//   u32 = pack(bf16 W[2k2][n], bf16 W[2k2+1][n]),  n = nb*64 + (slot ^ ((k2>>2)&3)<<4)
// A GEMM K-tile (32k x 64n) = 16 k2 rows = 4KB CONTIGUOUS in the blob.

__global__ __launch_bounds__(256) void k_wblock(const float* __restrict__ src,
    unsigned* __restrict__ dst, int K2, int N, int k2chunks) {
  int m   = blockIdx.x / k2chunks;
  int k2c = blockIdx.x % k2chunks;
  int t = threadIdx.x;
  int k2 = k2c * 8 + (t >> 5);
  int nbCount = N >> 6;
  const float* s0 = src + ((size_t)m * 2 * K2 + 2 * k2) * N;
  const float* s1 = s0 + N;
  unsigned* dbase = dst + (size_t)m * nbCount * K2 * 64;
  int x = ((k2 >> 2) & 3) << 4;
  for (int sB = (t & 31) * 8; sB < N; sB += 256) {
    int nb = sB >> 6;
    int n8 = (nb << 6) + ((sB & 63) ^ x);
    f4 a0 = *(const f4*)(s0 + n8); f4 a1 = *(const f4*)(s0 + n8 + 4);
    f4 b0 = *(const f4*)(s1 + n8); f4 b1 = *(const f4*)(s1 + n8 + 4);
    uint4v v0 = { pk2(a0[0], b0[0]), pk2(a0[1], b0[1]), pk2(a0[2], b0[2]), pk2(a0[3], b0[3]) };
    uint4v v1 = { pk2(a1[0], b1[0]), pk2(a1[1], b1[1]), pk2(a1[2], b1[2]), pk2(a1[3], b1[3]) };
    unsigned* d = dbase + ((size_t)nb * K2 + k2) * 64 + (sB & 63);
    *(uint4v*)d = v0;
    *(uint4v*)(d + 4) = v1;
  }
}

static __device__ __forceinline__ short8 bfragBlk(const unsigned* lB, int n, int kq) {
  uint4v v;
#pragma unroll
  for (int i = 0; i < 4; ++i) {
    int k2 = kq + i;
    v[i] = lB[k2 * 64 + (n ^ (((k2 >> 2) & 3) << 4))];
  }
  return __builtin_bit_cast(short8, v);
}

static __device__ __forceinline__ void mma2blk(const unsigned short* lA,
    const unsigned* lBg, const unsigned* lBu,
    f32x4 (&accg)[4][2], f32x4 (&accu)[4][2], int wm, int wn, int lane) {
  int r16 = lane & 15, kb = (lane >> 4) * 8, kq = (lane >> 4) * 4;
  short8 a[4], bg[2], bu[2];
#pragma unroll
  for (int mf = 0; mf < 4; ++mf) a[mf] = frag_ldA(lA, wm + mf * 16 + r16, kb);
#pragma unroll
  for (int nf = 0; nf < 2; ++nf) {
    int n = wn + nf * 16 + r16;
    bg[nf] = bfragBlk(lBg, n, kq);
    bu[nf] = bfragBlk(lBu, n, kq);
  }
#pragma unroll
  for (int mf = 0; mf < 4; ++mf)
#pragma unroll
    for (int nf = 0; nf < 2; ++nf) {
      accg[mf][nf] = __builtin_amdgcn_mfma_f32_16x16x32_bf16(a[mf], bg[nf], accg[mf][nf], 0, 0, 0);
      accu[mf][nf] = __builtin_amdgcn_mfma_f32_16x16x32_bf16(a[mf], bu[nf], accu[mf][nf], 0, 0, 0);
    }
}

static __device__ __forceinline__ void mma1blk(const unsigned short* lA, const unsigned* lB,
    f32x4 (&acc)[4][2], int wm, int wn, int lane) {
  int r16 = lane & 15, kb = (lane >> 4) * 8, kq = (lane >> 4) * 4;
  short8 a[4], b[2];
#pragma unroll
  for (int mf = 0; mf < 4; ++mf) a[mf] = frag_ldA(lA, wm + mf * 16 + r16, kb);
#pragma unroll
  for (int nf = 0; nf < 2; ++nf) b[nf] = bfragBlk(lB, wn + nf * 16 + r16, kq);
#pragma unroll
  for (int mf = 0; mf < 4; ++mf)
#pragma unroll
    for (int nf = 0; nf < 2; ++nf)
      acc[mf][nf] = __builtin_amdgcn_mfma_f32_16x16x32_bf16(a[mf], b[nf], acc[mf][nf], 0, 0, 0);
}

// ---- expert gate+up (blocked): grid 512 = 64e x 8nb --------------------
__global__ __launch_bounds__(256, 2) void k_gu_blk(const unsigned short* __restrict__ xbf,
    const unsigned* __restrict__ gblob, const unsigned* __restrict__ ublob,
    const int* __restrict__ cnt, const int* __restrict__ offs,
    const int* __restrict__ lists, unsigned short* __restrict__ hws) {
  int bid = blockIdx.x;
  int e = bid >> 3, nb = bid & 7, n0 = nb * 64;
  int ne = min(cnt[e], CAPC);
  if (ne == 0) return;
  const int* lst = lists + e * CAPC;
  int base = offs[e];
  __shared__ unsigned short lA[2][128 * 32];
  __shared__ unsigned lBg[2][16 * 64];
  __shared__ unsigned lBu[2][16 * 64];
  int tid = threadIdx.x, lane = tid & 63, wv = tid >> 6;
  int wm = (wv >> 1) * 64, wn = (wv & 1) * 32;
  const unsigned short* Abase = xbf; const int lda = DM;
  const unsigned* bg = gblob + (size_t)(e * 8 + nb) * 1024 * 64 + wv * 256 + lane * 4;
  const unsigned* bu = ublob + (size_t)(e * 8 + nb) * 1024 * 64 + wv * 256 + lane * 4;
  const int NT = 64;
  for (int m0 = 0; m0 < ne; m0 += 128) {
    A_SETUP(asrc, lst[min(m0 + row, ne - 1)])
    f32x4 accg[4][2] = {}; f32x4 accu[4][2] = {};
    A_STAGE(asrc, lA[0], 0)  GLDS16(bg, lBg[0] + wv * 256); GLDS16(bu, lBu[0] + wv * 256);
    A_STAGE(asrc, lA[1], 32) GLDS16(bg + 1024, lBg[1] + wv * 256); GLDS16(bu + 1024, lBu[1] + wv * 256);
    VMWAIT(4); BARX();
#pragma unroll 1
    for (int t = 0; t < NT; t += 2) {
      mma2blk(lA[0], lBg[0], lBu[0], accg, accu, wm, wn, lane);
      BARX();
      if (t + 2 < NT) {
        A_STAGE(asrc, lA[0], (t + 2) * 32)
        GLDS16(bg + (size_t)(t + 2) * 1024, lBg[0] + wv * 256);
        GLDS16(bu + (size_t)(t + 2) * 1024, lBu[0] + wv * 256);
        VMWAIT(4);
      } else { VMWAIT(0); }
      BARX();
      mma2blk(lA[1], lBg[1], lBu[1], accg, accu, wm, wn, lane);
      if (t + 2 < NT) {
        BARX();
        if (t + 3 < NT) {
          A_STAGE(asrc, lA[1], (t + 3) * 32)
          GLDS16(bg + (size_t)(t + 3) * 1024, lBg[1] + wv * 256);
          GLDS16(bu + (size_t)(t + 3) * 1024, lBu[1] + wv * 256);
          VMWAIT(4);
        } else { VMWAIT(0); }
        BARX();
      }
    }
    BARX();
#pragma unroll
    for (int mf = 0; mf < 4; ++mf)
#pragma unroll
      for (int r = 0; r < 4; ++r) {
        int rl = m0 + wm + mf * 16 + (lane >> 4) * 4 + r;
        if (rl < ne) {
#pragma unroll
          for (int nf = 0; nf < 2; ++nf) {
            int col = n0 + wn + nf * 16 + (lane & 15);
            float h = silu_mul(accg[mf][nf][r], accu[mf][nf][r]);
            hws[(size_t)(base + rl) * HEXP + col] = f2bf(h);
          }
        }
      }
  }
}

// ---- expert down (blocked): grid 2048 = 64e x 32nb ---------------------
__global__ __launch_bounds__(256, 2) void k_down_blk(const unsigned short* __restrict__ hws,
    const unsigned* __restrict__ dblob, const int* __restrict__ cnt, const int* __restrict__ offs,
    const int* __restrict__ lists, const float* __restrict__ wlist, float* __restrict__ out) {
  int bid = blockIdx.x;
  int e = bid >> 5, nb = bid & 31, n0 = nb * 64;
  int ne = min(cnt[e], CAPC);
  if (ne == 0) return;
  __shared__ unsigned short lA[2][128 * 32];
  __shared__ unsigned lB[2][16 * 64];
  int tid = threadIdx.x, lane = tid & 63, wv = tid >> 6;
  int wm = (wv >> 1) * 64, wn = (wv & 1) * 32;
  const unsigned short* Abase = hws + (size_t)offs[e] * HEXP; const int lda = HEXP;
  const unsigned* bb = dblob + (size_t)(e * 32 + nb) * 256 * 64 + wv * 256 + lane * 4;
  const int NT = 16;
  for (int m0 = 0; m0 < ne; m0 += 128) {
    A_SETUP(asrc, min(m0 + row, ne - 1))
    f32x4 acc[4][2] = {};
    A_STAGE(asrc, lA[0], 0)  GLDS16(bb, lB[0] + wv * 256);
    A_STAGE(asrc, lA[1], 32) GLDS16(bb + 1024, lB[1] + wv * 256);
    VMWAIT(3); BARX();
#pragma unroll 1
    for (int t = 0; t < NT; t += 2) {
      mma1blk(lA[0], lB[0], acc, wm, wn, lane);
      BARX();
      if (t + 2 < NT) {
        A_STAGE(asrc, lA[0], (t + 2) * 32)
        GLDS16(bb + (size_t)(t + 2) * 1024, lB[0] + wv * 256);
        VMWAIT(3);
      } else { VMWAIT(0); }
      BARX();
      mma1blk(lA[1], lB[1], acc, wm, wn, lane);
      if (t + 2 < NT) {
        BARX();
        if (t + 3 < NT) {
          A_STAGE(asrc, lA[1], (t + 3) * 32)
          GLDS16(bb + (size_t)(t + 3) * 1024, lB[1] + wv * 256);
          VMWAIT(3);
        } else { VMWAIT(0); }
        BARX();
      }
    }
    BARX();
#pragma unroll
    for (int mf = 0; mf < 4; ++mf)
#pragma unroll
      for (int r = 0; r < 4; ++r) {
        int rl = m0 + wm + mf * 16 + (lane >> 4) * 4 + r;
        if (rl < ne) {
          int tok = lists[e * CAPC + rl];
          float w = wlist[e * CAPC + rl];
#pragma unroll
          for (int nf = 0; nf < 2; ++nf) {
            int col = n0 + wn + nf * 16 + (lane & 15);
            atomicAdd(out + (size_t)tok * DM + col, acc[mf][nf][r] * w);
          }
        }
      }
  }
}

// ---- shared gate+up (blocked): grid 1024 = 2s x 16mb x 32nb ------------
__global__ __launch_bounds__(256, 2) void k_sgu_blk(const unsigned short* __restrict__ xbf,
    const unsigned* __restrict__ sgblob, const unsigned* __restrict__ sublob,
    unsigned short* __restrict__ hs) {
  int bid = blockIdx.x;
  int s = bid >> 9, mb = (bid >> 5) & 15, nb = bid & 31;
  int m0 = mb * 128, n0 = nb * 64;
  __shared__ unsigned short lA[2][128 * 32];
  __shared__ unsigned lBg[2][16 * 64];
  __shared__ unsigned lBu[2][16 * 64];
  int tid = threadIdx.x, lane = tid & 63, wv = tid >> 6;
  int wm = (wv >> 1) * 64, wn = (wv & 1) * 32;
  const unsigned short* Abase = xbf; const int lda = DM;
  const unsigned* bg = sgblob + (size_t)(s * 32 + nb) * 1024 * 64 + wv * 256 + lane * 4;
  const unsigned* bu = sublob + (size_t)(s * 32 + nb) * 1024 * 64 + wv * 256 + lane * 4;
  const int NT = 64;
  A_SETUP(asrc, m0 + row)
  f32x4 accg[4][2] = {}; f32x4 accu[4][2] = {};
  A_STAGE(asrc, lA[0], 0)  GLDS16(bg, lBg[0] + wv * 256); GLDS16(bu, lBu[0] + wv * 256);
  A_STAGE(asrc, lA[1], 32) GLDS16(bg + 1024, lBg[1] + wv * 256); GLDS16(bu + 1024, lBu[1] + wv * 256);
  VMWAIT(4); BARX();
#pragma unroll 1
  for (int t = 0; t < NT; t += 2) {
    mma2blk(lA[0], lBg[0], lBu[0], accg, accu, wm, wn, lane);
    BARX();
    if (t + 2 < NT) {
      A_STAGE(asrc, lA[0], (t + 2) * 32)
      GLDS16(bg + (size_t)(t + 2) * 1024, lBg[0] + wv * 256);
      GLDS16(bu + (size_t)(t + 2) * 1024, lBu[0] + wv * 256);
      VMWAIT(4);
    } else { VMWAIT(0); }
    BARX();
    mma2blk(lA[1], lBg[1], lBu[1], accg, accu, wm, wn, lane);
    if (t + 2 < NT) {
      BARX();
      if (t + 3 < NT) {
        A_STAGE(asrc, lA[1], (t + 3) * 32)
        GLDS16(bg + (size_t)(t + 3) * 1024, lBg[1] + wv * 256);
        GLDS16(bu + (size_t)(t + 3) * 1024, lBu[1] + wv * 256);
        VMWAIT(4);
      } else { VMWAIT(0); }
      BARX();
    }
  }
#pragma unroll
  for (int mf = 0; mf < 4; ++mf)
#pragma unroll
    for (int nf = 0; nf < 2; ++nf)
#pragma unroll
      for (int r = 0; r < 4; ++r) {
        int row = m0 + wm + mf * 16 + (lane >> 4) * 4 + r;
        int col = n0 + wn + nf * 16 + (lane & 15);
        float h = silu_mul(accg[mf][nf][r], accu[mf][nf][r]);
        hs[(size_t)row * (NSH * HSH) + s * HSH + col] = f2bf(h);
      }
}

// ---- shared down (blocked): grid 512 = 16mb x 32nb ---------------------
__global__ __launch_bounds__(256, 2) void k_sd_blk(const unsigned short* __restrict__ hs,
    const unsigned* __restrict__ sdblob, float* __restrict__ out) {
  int bid = blockIdx.x;
  int mb = bid >> 5, nb = bid & 31;
  int m0 = mb * 128, n0 = nb * 64;
  __shared__ unsigned short lA[2][128 * 32];
  __shared__ unsigned lB[2][16 * 64];
  int tid = threadIdx.x, lane = tid & 63, wv = tid >> 6;
  int wm = (wv >> 1) * 64, wn = (wv & 1) * 32;
  const unsigned short* Abase = hs; const int lda = NSH * HSH;
  const unsigned* bb = sdblob + (size_t)nb * 2048 * 64 + wv * 256 + lane * 4;
  const int NT = 128;
  A_SETUP(asrc, m0 + row)
  f32x4 acc[4][2] = {};
  A_STAGE(asrc, lA[0], 0)  GLDS16(bb, lB[0] + wv * 256);
  A_STAGE(asrc, lA[1], 32) GLDS16(bb + 1024, lB[1] + wv * 256);
  VMWAIT(3); BARX();
#pragma unroll 1
  for (int t = 0; t < NT; t += 2) {
    mma1blk(lA[0], lB[0], acc, wm, wn, lane);
    BARX();
    if (t + 2 < NT) {
      A_STAGE(asrc, lA[0], (t + 2) * 32)
      GLDS16(bb + (size_t)(t + 2) * 1024, lB[0] + wv * 256);
      VMWAIT(3);
    } else { VMWAIT(0); }
    BARX();
    mma1blk(lA[1], lB[1], acc, wm, wn, lane);
    if (t + 2 < NT) {
      BARX();
      if (t + 3 < NT) {
        A_STAGE(asrc, lA[1], (t + 3) * 32)
        GLDS16(bb + (size_t)(t + 3) * 1024, lB[1] + wv * 256);
        VMWAIT(3);
      } else { VMWAIT(0); }
      BARX();
    }
  }
#pragma unroll
  for (int mf = 0; mf < 4; ++mf)
#pragma unroll
    for (int nf = 0; nf < 2; ++nf)
#pragma unroll
      for (int r = 0; r < 4; ++r) {
        int row = m0 + wm + mf * 16 + (lane >> 4) * 4 + r;
        int col = n0 + wn + nf * 16 + (lane & 15);
        out[(size_t)row * DM + col] = acc[mf][nf][r];
      }
}

// ================================================================ FALLBACK (R4, fp32 weights)
static __device__ __forceinline__ short8 bfragB(const float* lB, int nl, int kb) {
  const float* p = lB + kb * 64 + (nl ^ (((kb >> 3) & 1) << 4));
  float f0 = p[0],   f1 = p[64],  f2 = p[128], f3 = p[192];
  float f4_ = p[256], f5 = p[320], f6 = p[384], f7 = p[448];
  uint4v uv = { pk2(f0, f1), pk2(f2, f3), pk2(f4_, f5), pk2(f6, f7) };
  return __builtin_bit_cast(short8, uv);
}

static __device__ __forceinline__ void mma1f(const unsigned short* lA, const float* lB,
    f32x4 (&acc)[4][2], int wm, int wn, int lane) {
  int r16 = lane & 15;
  int kb  = (lane >> 4) * 8;
  short8 a[4], b[2];
#pragma unroll
  for (int mf = 0; mf < 4; ++mf) a[mf] = frag_ldA(lA, wm + mf * 16 + r16, kb);
#pragma unroll
  for (int nf = 0; nf < 2; ++nf) b[nf] = bfragB(lB, wn + nf * 16 + r16, kb);
#pragma unroll
  for (int mf = 0; mf < 4; ++mf)
#pragma unroll
    for (int nf = 0; nf < 2; ++nf)
      acc[mf][nf] = __builtin_amdgcn_mfma_f32_16x16x32_bf16(a[mf], b[nf], acc[mf][nf], 0, 0, 0);
}

static __device__ __forceinline__ void mma2f(const unsigned short* lA,
    const float* lBg, const float* lBu,
    f32x4 (&accg)[4][2], f32x4 (&accu)[4][2], int wm, int wn, int lane) {
  int r16 = lane & 15;
  int kb  = (lane >> 4) * 8;
  short8 a[4], bg[2], bu[2];
#pragma unroll
  for (int mf = 0; mf < 4; ++mf) a[mf] = frag_ldA(lA, wm + mf * 16 + r16, kb);
#pragma unroll
  for (int nf = 0; nf < 2; ++nf) {
    bg[nf] = bfragB(lBg, wn + nf * 16 + r16, kb);
    bu[nf] = bfragB(lBu, wn + nf * 16 + r16, kb);
  }
#pragma unroll
  for (int mf = 0; mf < 4; ++mf)
#pragma unroll
    for (int nf = 0; nf < 2; ++nf) {
      accg[mf][nf] = __builtin_amdgcn_mfma_f32_16x16x32_bf16(a[mf], bg[nf], accg[mf][nf], 0, 0, 0);
      accu[mf][nf] = __builtin_amdgcn_mfma_f32_16x16x32_bf16(a[mf], bu[nf], accu[mf][nf], 0, 0, 0);
    }
}

#define B_SETUP(bsrc, Bbase, ldb)                                           \
  const float* bsrc[2];                                                     \
  {                                                                         \
    _Pragma("unroll")                                                       \
    for (int p = 0; p < 2; ++p) {                                           \
      int k = p * 16 + wv * 4 + (lane >> 4);                                \
      int c = (lane & 15) ^ (((k >> 3) & 1) << 2);                          \
      bsrc[p] = (Bbase) + (size_t)k * (ldb) + n0 + c * 4;                   \
    }                                                                       \
  }
#define B_STAGE(bsrc, lBbuf, k0, ldb)                                       \
  { _Pragma("unroll")                                                       \
    for (int p = 0; p < 2; ++p)                                             \
      GLDS16(bsrc[p] + (size_t)(k0) * (ldb), (lBbuf) + p * 1024 + wv * 256); }

__global__ __launch_bounds__(256, 3) void k_gu_fb(const unsigned short* __restrict__ xbf,
    const float* __restrict__ Wg, const float* __restrict__ Wu,
    const int* __restrict__ cnt, const int* __restrict__ offs,
    const int* __restrict__ lists, unsigned short* __restrict__ hws) {
  int e = blockIdx.y;
  int ne = min(cnt[e], CAPC);
  if (ne == 0) return;
  int n0 = blockIdx.x * 64;
  const float* Bg = Wg + (size_t)e * DM * HEXP;
  const float* Bu = Wu + (size_t)e * DM * HEXP;
  const int* lst = lists + e * CAPC;
  int base = offs[e];
  __shared__ unsigned short lA[2][128 * 32];
  __shared__ float lBg[2][32 * 64];
  __shared__ float lBu[2][32 * 64];
  int tid = threadIdx.x, lane = tid & 63, wv = tid >> 6;
  int wm = (wv >> 1) * 64, wn = (wv & 1) * 32;
  const unsigned short* Abase = xbf; const int lda = DM;
  B_SETUP(bgsrc, Bg, HEXP)
  B_SETUP(busrc, Bu, HEXP)
  const int NT = DM / 32;
  for (int m0 = 0; m0 < ne; m0 += 128) {
    A_SETUP(asrc, lst[min(m0 + row, ne - 1)])
    f32x4 accg[4][2] = {};
    f32x4 accu[4][2] = {};
    A_STAGE(asrc, lA[0], 0)  B_STAGE(bgsrc, lBg[0], 0, HEXP)  B_STAGE(busrc, lBu[0], 0, HEXP)
    A_STAGE(asrc, lA[1], 32) B_STAGE(bgsrc, lBg[1], 32, HEXP) B_STAGE(busrc, lBu[1], 32, HEXP)
    VMWAIT(6); BARX();
#pragma unroll 1
    for (int t = 0; t < NT; t += 2) {
      mma2f(lA[0], lBg[0], lBu[0], accg, accu, wm, wn, lane);
      BARX();
      if (t + 2 < NT) {
        int k2 = (t + 2) * 32;
        A_STAGE(asrc, lA[0], k2) B_STAGE(bgsrc, lBg[0], k2, HEXP) B_STAGE(busrc, lBu[0], k2, HEXP)
        VMWAIT(6);
      } else { VMWAIT(0); }
      BARX();
      mma2f(lA[1], lBg[1], lBu[1], accg, accu, wm, wn, lane);
      if (t + 2 < NT) {
        BARX();
        if (t + 3 < NT) {
          int k3 = (t + 3) * 32;
          A_STAGE(asrc, lA[1], k3) B_STAGE(bgsrc, lBg[1], k3, HEXP) B_STAGE(busrc, lBu[1], k3, HEXP)
          VMWAIT(6);
        } else { VMWAIT(0); }
        BARX();
      }
    }
    BARX();
#pragma unroll
    for (int mf = 0; mf < 4; ++mf)
#pragma unroll
      for (int r = 0; r < 4; ++r) {
        int rl = m0 + wm + mf * 16 + (lane >> 4) * 4 + r;
        if (rl < ne) {
#pragma unroll
          for (int nf = 0; nf < 2; ++nf) {
            int col = n0 + wn + nf * 16 + (lane & 15);
            float h = silu_mul(accg[mf][nf][r], accu[mf][nf][r]);
            hws[(size_t)(base + rl) * HEXP + col] = f2bf(h);
          }
        }
      }
  }
}

__global__ __launch_bounds__(256, 3) void k_sgu_fb(const unsigned short* __restrict__ xbf,
    const float* __restrict__ Sg, const float* __restrict__ Su,
    unsigned short* __restrict__ hs) {
  int n0 = blockIdx.x * 64;
  int m0 = blockIdx.y * 128;
  int s  = blockIdx.z;
  const float* Bg = Sg + (size_t)s * DM * HSH;
  const float* Bu = Su + (size_t)s * DM * HSH;
  __shared__ unsigned short lA[2][128 * 32];
  __shared__ float lBg[2][32 * 64];
  __shared__ float lBu[2][32 * 64];
  int tid = threadIdx.x, lane = tid & 63, wv = tid >> 6;
  int wm = (wv >> 1) * 64, wn = (wv & 1) * 32;
  const unsigned short* Abase = xbf; const int lda = DM;
  B_SETUP(bgsrc, Bg, HSH)
  B_SETUP(busrc, Bu, HSH)
  A_SETUP(asrc, m0 + row)
  f32x4 accg[4][2] = {};
  f32x4 accu[4][2] = {};
  const int NT = DM / 32;
  A_STAGE(asrc, lA[0], 0)  B_STAGE(bgsrc, lBg[0], 0, HSH)  B_STAGE(busrc, lBu[0], 0, HSH)
  A_STAGE(asrc, lA[1], 32) B_STAGE(bgsrc, lBg[1], 32, HSH) B_STAGE(busrc, lBu[1], 32, HSH)
  VMWAIT(6); BARX();
#pragma unroll 1
  for (int t = 0; t < NT; t += 2) {
    mma2f(lA[0], lBg[0], lBu[0], accg, accu, wm, wn, lane);
    BARX();
    if (t + 2 < NT) {
      int k2 = (t + 2) * 32;
      A_STAGE(asrc, lA[0], k2) B_STAGE(bgsrc, lBg[0], k2, HSH) B_STAGE(busrc, lBu[0], k2, HSH)
      VMWAIT(6);
    } else { VMWAIT(0); }
    BARX();
    mma2f(lA[1], lBg[1], lBu[1], accg, accu, wm, wn, lane);
    if (t + 2 < NT) {
      BARX();
      if (t + 3 < NT) {
        int k3 = (t + 3) * 32;
        A_STAGE(asrc, lA[1], k3) B_STAGE(bgsrc, lBg[1], k3, HSH) B_STAGE(busrc, lBu[1], k3, HSH)
        VMWAIT(6);
      } else { VMWAIT(0); }
      BARX();
    }
  }
#pragma unroll
  for (int mf = 0; mf < 4; ++mf)
#pragma unroll
    for (int nf = 0; nf < 2; ++nf)
#pragma unroll
      for (int r = 0; r < 4; ++r) {
        int row = m0 + wm + mf * 16 + (lane >> 4) * 4 + r;
        int col = n0 + wn + nf * 16 + (lane & 15);
        float h = silu_mul(accg[mf][nf][r], accu[mf][nf][r]);
        hs[(size_t)row * (NSH * HSH) + s * HSH + col] = f2bf(h);
      }
}

__global__ __launch_bounds__(256, 4) void k_sd_fb(const unsigned short* __restrict__ hs,
    const float* __restrict__ Sd, float* __restrict__ out) {
  int n0 = blockIdx.x * 64;
  int m0 = blockIdx.y * 128;
  __shared__ unsigned short lA[2][128 * 32];
  __shared__ float lB[2][32 * 64];
  int tid = threadIdx.x, lane = tid & 63, wv = tid >> 6;
  int wm = (wv >> 1) * 64, wn = (wv & 1) * 32;
  const unsigned short* Abase = hs; const int lda = NSH * HSH;
  B_SETUP(bsrc, Sd, DM)
  A_SETUP(asrc, m0 + row)
  f32x4 acc[4][2] = {};
  const int NT = (NSH * HSH) / 32;
  A_STAGE(asrc, lA[0], 0)  B_STAGE(bsrc, lB[0], 0, DM)
  A_STAGE(asrc, lA[1], 32) B_STAGE(bsrc, lB[1], 32, DM)
  VMWAIT(4); BARX();
#pragma unroll 1
  for (int t = 0; t < NT; t += 2) {
    mma1f(lA[0], lB[0], acc, wm, wn, lane);
    BARX();
    if (t + 2 < NT) {
      int k2 = (t + 2) * 32;
      A_STAGE(asrc, lA[0], k2) B_STAGE(bsrc, lB[0], k2, DM)
      VMWAIT(4);
    } else { VMWAIT(0); }
    BARX();
    mma1f(lA[1], lB[1], acc, wm, wn, lane);
    if (t + 2 < NT) {
      BARX();
      if (t + 3 < NT) {
        int k3 = (t + 3) * 32;
        A_STAGE(asrc, lA[1], k3) B_STAGE(bsrc, lB[1], k3, DM)
        VMWAIT(4);
      } else { VMWAIT(0); }
      BARX();
    }
  }
#pragma unroll
  for (int mf = 0; mf < 4; ++mf)
#pragma unroll
    for (int nf = 0; nf < 2; ++nf)
#pragma unroll
      for (int r = 0; r < 4; ++r) {
        int row = m0 + wm + mf * 16 + (lane >> 4) * 4 + r;
        int col = n0 + wn + nf * 16 + (lane & 15);
        out[(size_t)row * DM + col] = acc[mf][nf][r];
      }
}

__global__ __launch_bounds__(256, 4) void k_down_fb(const unsigned short* __restrict__ hws,
    const float* __restrict__ Wd, const int* __restrict__ cnt, const int* __restrict__ offs,
    const int* __restrict__ lists, const float* __restrict__ wlist,
    float* __restrict__ out) {
  int e = blockIdx.y;
  int ne = min(cnt[e], CAPC);
  if (ne == 0) return;
  int n0 = blockIdx.x * 64;
  const float* B = Wd + (size_t)e * HEXP * DM;
  __shared__ unsigned short lA[2][128 * 32];
  __shared__ float lB[2][32 * 64];
  int tid = threadIdx.x, lane = tid & 63, wv = tid >> 6;
  int wm = (wv >> 1) * 64, wn = (wv & 1) * 32;
  const unsigned short* Abase = hws + (size_t)offs[e] * HEXP; const int lda = HEXP;
  B_SETUP(bsrc, B, DM)
  const int NT = HEXP / 32;
  for (int m0 = 0; m0 < ne; m0 += 128) {
    A_SETUP(asrc, min(m0 + row, ne - 1))
    f32x4 acc[4][2] = {};
    A_STAGE(asrc, lA[0], 0)  B_STAGE(bsrc, lB[0], 0, DM)
    A_STAGE(asrc, lA[1], 32) B_STAGE(bsrc, lB[1], 32, DM)
    VMWAIT(4); BARX();
#pragma unroll 1
    for (int t = 0; t < NT; t += 2) {
      mma1f(lA[0], lB[0], acc, wm, wn, lane);
      BARX();
      if (t + 2 < NT) {
        int k2 = (t + 2) * 32;
        A_STAGE(asrc, lA[0], k2) B_STAGE(bsrc, lB[0], k2, DM)
        VMWAIT(4);
      } else { VMWAIT(0); }
      BARX();
      mma1f(lA[1], lB[1], acc, wm, wn, lane);
      if (t + 2 < NT) {
        BARX();
        if (t + 3 < NT) {
          int k3 = (t + 3) * 32;
          A_STAGE(asrc, lA[1], k3) B_STAGE(bsrc, lB[1], k3, DM)
          VMWAIT(4);
        } else { VMWAIT(0); }
        BARX();
      }
    }
    BARX();
#pragma unroll
    for (int mf = 0; mf < 4; ++mf)
#pragma unroll
      for (int r = 0; r < 4; ++r) {
        int rl = m0 + wm + mf * 16 + (lane >> 4) * 4 + r;
        if (rl < ne) {
          int tok  = lists[e * CAPC + rl];
          float w  = wlist[e * CAPC + rl];
#pragma unroll
          for (int nf = 0; nf < 2; ++nf) {
            int col = n0 + wn + nf * 16 + (lane & 15);
            atomicAdd(out + (size_t)tok * DM + col, acc[mf][nf][r] * w);
          }
        }
      }
  }
}

// ---------------------------------------------------------------- launch
extern "C" void kernel_launch(void* const* d_in, const int* in_sizes, int n_in,
                              void* d_out, int out_size, void* d_ws, size_t ws_size,
                              hipStream_t stream) {
  const float* x    = (const float*)d_in[0];
  const float* Wr   = (const float*)d_in[1];
  const float* bias = (const float*)d_in[2];
  const float* Wg   = (const float*)d_in[3];
  const float* Wu   = (const float*)d_in[4];
  const float* Wd   = (const float*)d_in[5];
  const float* Sg   = (const float*)d_in[6];
  const float* Su   = (const float*)d_in[7];
  const float* Sd   = (const float*)d_in[8];
  float* out = (float*)d_out;
  char* ws = (char*)d_ws;

  const size_t off_cnt   = 0;
  const size_t off_offs  = 256;
  const size_t off_lists = 1024;
  const size_t off_wlist = off_lists + (size_t)NEXP * CAPC * 4;
  const size_t off_xbf   = off_wlist + (size_t)NEXP * CAPC * 4;
  const size_t off_hs    = off_xbf + (size_t)N_TOK * DM * 2;
  const size_t off_h     = off_hs + (size_t)N_TOK * NSH * HSH * 2;
  const size_t off_blob  = (off_h + (size_t)N_TOK * TOPK * HEXP * 2 + 255) & ~(size_t)255;
  const size_t GB = (size_t)64 * 8 * 1024 * 64 * 4;     // 128 MiB (Wg blob)
  const size_t SB = (size_t)64 * 1024 * 64 * 4;         // 16 MiB  (Sg blob)
  const size_t off_g  = off_blob;
  const size_t off_u  = off_g + GB;
  const size_t off_d  = off_u + GB;
  const size_t off_sg = off_d + GB;
  const size_t off_su = off_sg + SB;
  const size_t off_sd = off_su + SB;
  const size_t req_blk = off_sd + SB;
  const size_t req_fb  = off_blob;
  if (ws_size < req_fb) return;

  int* cnt            = (int*)(ws + off_cnt);
  int* offs           = (int*)(ws + off_offs);
  int* lists          = (int*)(ws + off_lists);
  float* wlist        = (float*)(ws + off_wlist);
  unsigned short* xbf = (unsigned short*)(ws + off_xbf);
  unsigned short* hs  = (unsigned short*)(ws + off_hs);
  unsigned short* hws = (unsigned short*)(ws + off_h);

  hipMemsetAsync(cnt, 0, NEXP * sizeof(int), stream);
  k_convert<<<(N_TOK * DM) / (256 * 8), 256, 0, stream>>>(x, xbf);
  k_router<<<N_TOK / RTB, 256, 0, stream>>>(x, Wr, bias, cnt, lists, wlist);
  k_offs<<<1, 64, 0, stream>>>(cnt, offs);

  if (ws_size >= req_blk) {
    unsigned* gblob  = (unsigned*)(ws + off_g);
    unsigned* ublob  = (unsigned*)(ws + off_u);
    unsigned* dblob  = (unsigned*)(ws + off_d);
    unsigned* sgblob = (unsigned*)(ws + off_sg);
    unsigned* sublob = (unsigned*)(ws + off_su);
    unsigned* sdblob = (unsigned*)(ws + off_sd);
    k_wblock<<<64 * 128, 256, 0, stream>>>(Wg, gblob, 1024, 512, 128);
    k_wblock<<<64 * 128, 256, 0, stream>>>(Wu, ublob, 1024, 512, 128);
    k_wblock<<<64 * 32, 256, 0, stream>>>(Wd, dblob, 256, 2048, 32);
    k_wblock<<<2 * 128, 256, 0, stream>>>(Sg, sgblob, 1024, 2048, 128);
    k_wblock<<<2 * 128, 256, 0, stream>>>(Su, sublob, 1024, 2048, 128);
    k_wblock<<<256, 256, 0, stream>>>(Sd, sdblob, 2048, 2048, 256);
    k_gu_blk<<<512, 256, 0, stream>>>(xbf, gblob, ublob, cnt, offs, lists, hws);
    k_sgu_blk<<<1024, 256, 0, stream>>>(xbf, sgblob, sublob, hs);
    k_sd_blk<<<512, 256, 0, stream>>>(hs, sdblob, out);
    k_down_blk<<<2048, 256, 0, stream>>>(hws, dblob, cnt, offs, lists, wlist, out);
  } else {
    k_gu_fb<<<dim3(HEXP / 64, NEXP), 256, 0, stream>>>(xbf, Wg, Wu, cnt, offs, lists, hws);
    k_sgu_fb<<<dim3(HSH / 64, N_TOK / 128, NSH), 256, 0, stream>>>(xbf, Sg, Su, hs);
    k_sd_fb<<<dim3(DM / 64, N_TOK / 128), 256, 0, stream>>>(hs, Sd, out);
    k_down_fb<<<dim3(DM / 64, NEXP), 256, 0, stream>>>(hws, Wd, cnt, offs, lists, wlist, out);
  }
}

// Round 11
// 712.212 us; speedup vs baseline: 1.0838x; 1.0838x over previous
//
#include <hip/hip_runtime.h>
#include <hip/hip_bf16.h>
#include <stdint.h>

#define N_TOK 2048
#define DM    2048
#define NEXP  64
#define TOPK  4
#define HEXP  512
#define CAPC  512
#define NSH   2
#define HSH   2048
#define RTB   8

typedef __attribute__((ext_vector_type(8))) short short8;
typedef __attribute__((ext_vector_type(4))) float f32x4;
typedef __attribute__((ext_vector_type(4))) float f4;
typedef __attribute__((ext_vector_type(4))) unsigned uint4v;

#define GLDS16(g, l) __builtin_amdgcn_global_load_lds(                     \
    (const __attribute__((address_space(1))) void*)(g),                    \
    (__attribute__((address_space(3))) void*)(l), 16, 0, 0)

#define VMWAIT(N) asm volatile("s_waitcnt vmcnt(" #N ")" ::: "memory")
#define BARX() do { asm volatile("" ::: "memory");                          \
                    __builtin_amdgcn_s_barrier();                           \
                    asm volatile("" ::: "memory"); } while (0)

static __device__ __forceinline__ unsigned short f2bf(float f) {
  union { float f; unsigned u; } v; v.f = f;
  unsigned r = v.u + 0x7FFFu + ((v.u >> 16) & 1u);   // RNE
  return (unsigned short)(r >> 16);
}

static __device__ __forceinline__ unsigned pk2(float lo, float hi) {
  unsigned u;
  asm("v_cvt_pk_bf16_f32 %0, %1, %2" : "=v"(u) : "v"(lo), "v"(hi));
  return u;
}

// ---------------------------------------------------------------- convert x
__global__ __launch_bounds__(256) void k_convert(const float* __restrict__ x,
                                                 unsigned short* __restrict__ xb) {
  int i = (blockIdx.x * 256 + threadIdx.x) * 8;
  f4 a = *(const f4*)(x + i);
  f4 b = *(const f4*)(x + i + 4);
  short8 o;
  o[0]=f2bf(a[0]); o[1]=f2bf(a[1]); o[2]=f2bf(a[2]); o[3]=f2bf(a[3]);
  o[4]=f2bf(b[0]); o[5]=f2bf(b[1]); o[6]=f2bf(b[2]); o[7]=f2bf(b[3]);
  *(short8*)(xb + i) = o;
}

// ---------------------------------------------------------------- router
#define ARGMAX_ROUND(S,I)                                            \
  { float bv = v; int bi = lane;                                     \
    _Pragma("unroll")                                                \
    for (int o = 32; o; o >>= 1) {                                   \
      float ov = __shfl_xor(bv, o); int oi = __shfl_xor(bi, o);      \
      if (ov > bv || (ov == bv && oi < bi)) { bv = ov; bi = oi; }    \
    }                                                                \
    S = bv; I = bi; if (lane == bi) v = -1.f; }

__global__ __launch_bounds__(256) void k_router(const float* __restrict__ x,
    const float* __restrict__ Wr, const float* __restrict__ bias,
    int* __restrict__ cnt, int* __restrict__ lists, float* __restrict__ wlist) {
  __shared__ float part[4][RTB][64];
  __shared__ float logits[RTB][64];
  int t = threadIdx.x;
  int e = t & 63, sl = t >> 6;
  int tok0 = blockIdx.x * RTB;
  const float* xp = x + (size_t)tok0 * DM;
  float acc[RTB];
#pragma unroll
  for (int i = 0; i < RTB; ++i) acc[i] = 0.f;
  for (int d = sl * 512; d < sl * 512 + 512; ++d) {
    float w = Wr[(size_t)d * NEXP + e];
#pragma unroll
    for (int i = 0; i < RTB; ++i) acc[i] += xp[(size_t)i * DM + d] * w;
  }
#pragma unroll
  for (int i = 0; i < RTB; ++i) part[sl][i][e] = acc[i];
  __syncthreads();
  for (int i = sl; i < RTB; i += 4)
    logits[i][e] = part[0][i][e] + part[1][i][e] + part[2][i][e] + part[3][i][e] + bias[e];
  __syncthreads();
  int lane = t & 63, wv = t >> 6;
  for (int i = wv * 2; i < wv * 2 + 2; ++i) {
    float lg = logits[i][lane];
    float m = lg;
#pragma unroll
    for (int o = 32; o; o >>= 1) m = fmaxf(m, __shfl_xor(m, o));
    float p = expf(lg - m);
    float sm = p;
#pragma unroll
    for (int o = 32; o; o >>= 1) sm += __shfl_xor(sm, o);
    float v = p / sm;
    float s0, s1, s2, s3; int i0, i1, i2, i3;
    ARGMAX_ROUND(s0, i0)
    ARGMAX_ROUND(s1, i1)
    ARGMAX_ROUND(s2, i2)
    ARGMAX_ROUND(s3, i3)
    float tot = s0 + s1 + s2 + s3;
    if (lane < TOPK) {
      float myw = (lane == 0 ? s0 : lane == 1 ? s1 : lane == 2 ? s2 : s3) / tot;
      int   mye = (lane == 0 ? i0 : lane == 1 ? i1 : lane == 2 ? i2 : i3);
      int pos = atomicAdd(&cnt[mye], 1);
      if (pos < CAPC) {
        lists[mye * CAPC + pos] = tok0 + i;
        wlist[mye * CAPC + pos] = myw;
      }
    }
  }
}

// ---------------------------------------------------------------- offsets
__global__ void k_offs(const int* __restrict__ cnt, int* __restrict__ offs) {
  int l = threadIdx.x;
  int c = min(cnt[l], CAPC);
  int sum = c;
#pragma unroll
  for (int o = 1; o < 64; o <<= 1) {
    int ov = __shfl_up(sum, o);
    if (l >= o) sum += ov;
  }
  offs[l + 1] = sum;
  if (l == 0) offs[0] = 0;
}

// ---------------------------------------------------------------- frag helpers (R4-proven)
static __device__ __forceinline__ short8 frag_ldA(const unsigned short* lds, int row, int kElem) {
  int byte = row * 64 + kElem * 2;
  byte ^= ((row >> 1) & 3) << 4;
  return *(const short8*)((const char*)lds + byte);
}

static __device__ __forceinline__ short8 bfragB(const float* lB, int nl, int kb) {
  const float* p = lB + kb * 64 + (nl ^ (((kb >> 3) & 1) << 4));
  float f0 = p[0],   f1 = p[64],  f2 = p[128], f3 = p[192];
  float f4_ = p[256], f5 = p[320], f6 = p[384], f7 = p[448];
  uint4v uv = { pk2(f0, f1), pk2(f2, f3), pk2(f4_, f5), pk2(f6, f7) };
  return __builtin_bit_cast(short8, uv);
}

static __device__ __forceinline__ void mma1f(const unsigned short* lA, const float* lB,
    f32x4 (&acc)[4][2], int wm, int wn, int lane) {
  int r16 = lane & 15;
  int kb  = (lane >> 4) * 8;
  short8 a[4], b[2];
#pragma unroll
  for (int mf = 0; mf < 4; ++mf) a[mf] = frag_ldA(lA, wm + mf * 16 + r16, kb);
#pragma unroll
  for (int nf = 0; nf < 2; ++nf) b[nf] = bfragB(lB, wn + nf * 16 + r16, kb);
#pragma unroll
  for (int mf = 0; mf < 4; ++mf)
#pragma unroll
    for (int nf = 0; nf < 2; ++nf)
      acc[mf][nf] = __builtin_amdgcn_mfma_f32_16x16x32_bf16(a[mf], b[nf], acc[mf][nf], 0, 0, 0);
}

static __device__ __forceinline__ float silu_mul(float g, float u) {
  return g / (1.f + expf(-g)) * u;
}

// ---------------------------------------------------------------- staging macros (R4-proven)
#define A_SETUP(asrc, SROW_EXPR)                                            \
  const unsigned short* asrc[2];                                            \
  {                                                                         \
    _Pragma("unroll")                                                       \
    for (int p = 0; p < 2; ++p) {                                           \
      int row = p * 64 + wv * 16 + (lane >> 2);                             \
      int srow = (SROW_EXPR);                                               \
      asrc[p] = Abase + (size_t)srow * lda                                  \
              + (((lane & 3) ^ ((row >> 1) & 3)) << 3);                     \
    }                                                                       \
  }
#define A_STAGE(asrc, lAbuf, k0)                                            \
  { _Pragma("unroll")                                                       \
    for (int p = 0; p < 2; ++p)                                             \
      GLDS16(asrc[p] + (k0), (lAbuf) + p * 2048 + wv * 512); }

#define B_SETUP(bsrc, Bbase, ldb)                                           \
  const float* bsrc[2];                                                     \
  {                                                                         \
    _Pragma("unroll")                                                       \
    for (int p = 0; p < 2; ++p) {                                           \
      int k = p * 16 + wv * 4 + (lane >> 4);                                \
      int c = (lane & 15) ^ (((k >> 3) & 1) << 2);                          \
      bsrc[p] = (Bbase) + (size_t)k * (ldb) + n0 + c * 4;                   \
    }                                                                       \
  }
#define B_STAGE(bsrc, lBbuf, k0, ldb)                                       \
  { _Pragma("unroll")                                                       \
    for (int p = 0; p < 2; ++p)                                             \
      GLDS16(bsrc[p] + (size_t)(k0) * (ldb), (lBbuf) + p * 1024 + wv * 256); }

// 4-deep pipeline step: per tile/wave 4 GLDS ops (A2 + B2).
// Steady state: 16 ops (4 tiles) in flight; VMWAIT(12) => oldest tile landed,
// 3 tiles (48 KB/block) stay in flight across barriers and MFMA.
#define MM_STEP(q, tn, LDB)                                                 \
  VMWAIT(12); BARX();                                                       \
  mma1f(lA[q], lB[q], acc, wm, wn, lane);                                   \
  BARX();                                                                   \
  A_STAGE(asrc, lA[q], (tn) * 32)                                           \
  B_STAGE(bsrc, lB[q], (tn) * 32, LDB)

#define MM_PEEL(q, W)                                                       \
  VMWAIT(W); BARX();                                                        \
  mma1f(lA[q], lB[q], acc, wm, wn, lane);

// ---------------------------------------------------------------- expert gate/up GEMM
// grid 1024 = (mat 2) x (e 64) x (nb 8); all 16 blocks of expert e share bid&7
// (XCD co-location for A re-reads and DRAM-row sharing).
__global__ __launch_bounds__(256, 2) void k_mmE(const unsigned short* __restrict__ xbf,
    const float* __restrict__ Wg, const float* __restrict__ Wu,
    const int* __restrict__ cnt, const int* __restrict__ offs,
    const int* __restrict__ lists, unsigned short* __restrict__ hg,
    unsigned short* __restrict__ hu) {
  int bid = blockIdx.x;
  int e   = ((bid & 7) << 3) | ((bid >> 3) & 7);
  int nb  = (bid >> 6) & 7;
  int mat = bid >> 9;
  int n0 = nb * 64;
  int ne = min(cnt[e], CAPC);
  if (ne == 0) return;
  const float* B = (mat ? Wu : Wg) + (size_t)e * DM * HEXP;
  unsigned short* hdst = mat ? hu : hg;
  const int* lst = lists + e * CAPC;
  int base = offs[e];
  __shared__ unsigned short lA[4][128 * 32];
  __shared__ float lB[4][32 * 64];
  int tid = threadIdx.x, lane = tid & 63, wv = tid >> 6;
  int wm = (wv >> 1) * 64, wn = (wv & 1) * 32;
  const unsigned short* Abase = xbf; const int lda = DM;
  B_SETUP(bsrc, B, HEXP)
  const int NT = DM / 32;   // 64
  for (int m0 = 0; m0 < ne; m0 += 128) {
    A_SETUP(asrc, lst[min(m0 + row, ne - 1)])
    f32x4 acc[4][2] = {};
#pragma unroll
    for (int q = 0; q < 4; ++q) {
      A_STAGE(asrc, lA[q], q * 32)
      B_STAGE(bsrc, lB[q], q * 32, HEXP)
    }
#pragma unroll 1
    for (int t = 0; t < NT - 4; t += 4) {
      MM_STEP(0, t + 4, HEXP)
      MM_STEP(1, t + 5, HEXP)
      MM_STEP(2, t + 6, HEXP)
      MM_STEP(3, t + 7, HEXP)
    }
    MM_PEEL(0, 12) MM_PEEL(1, 8) MM_PEEL(2, 4) MM_PEEL(3, 0)
    BARX();
#pragma unroll
    for (int mf = 0; mf < 4; ++mf)
#pragma unroll
      for (int r = 0; r < 4; ++r) {
        int rl = m0 + wm + mf * 16 + (lane >> 4) * 4 + r;
        if (rl < ne) {
#pragma unroll
          for (int nf = 0; nf < 2; ++nf) {
            int col = n0 + wn + nf * 16 + (lane & 15);
            hdst[(size_t)(base + rl) * HEXP + col] = f2bf(acc[mf][nf][r]);
          }
        }
      }
  }
}

// ---------------------------------------------------------------- expert swiglu
__global__ __launch_bounds__(256) void k_swiglu_e(const unsigned short* __restrict__ hg,
    const unsigned short* __restrict__ hu, const int* __restrict__ offs,
    unsigned short* __restrict__ hws) {
  int total = offs[NEXP];
  int gid = blockIdx.x * 256 + threadIdx.x;
  int row = gid >> 6;
  if (row >= total) return;
  int c0 = (gid & 63) * 8;
  size_t o = (size_t)row * HEXP + c0;
  short8 g8 = *(const short8*)(hg + o);
  short8 u8 = *(const short8*)(hu + o);
  short8 r;
#pragma unroll
  for (int j = 0; j < 8; ++j) {
    union { unsigned u; float f; } gg, uu;
    gg.u = ((unsigned)(unsigned short)g8[j]) << 16;
    uu.u = ((unsigned)(unsigned short)u8[j]) << 16;
    r[j] = f2bf(silu_mul(gg.f, uu.f));
  }
  *(short8*)(hws + o) = r;
}

// ---------------------------------------------------------------- shared gate/up GEMM
// grid 2048 = (mat 2) x (s 2) x (mb 16) x (nb 32)
__global__ __launch_bounds__(256, 2) void k_mmS(const unsigned short* __restrict__ xbf,
    const float* __restrict__ Sg, const float* __restrict__ Su,
    unsigned short* __restrict__ hsg, unsigned short* __restrict__ hsu) {
  int bid = blockIdx.x;
  int nb = bid & 31, mb = (bid >> 5) & 15, s = (bid >> 9) & 1, mat = bid >> 10;
  int n0 = nb * 64, m0 = mb * 128;
  const float* B = (mat ? Su : Sg) + (size_t)s * DM * HSH;
  unsigned short* hdst = mat ? hsu : hsg;
  __shared__ unsigned short lA[4][128 * 32];
  __shared__ float lB[4][32 * 64];
  int tid = threadIdx.x, lane = tid & 63, wv = tid >> 6;
  int wm = (wv >> 1) * 64, wn = (wv & 1) * 32;
  const unsigned short* Abase = xbf; const int lda = DM;
  B_SETUP(bsrc, B, HSH)
  A_SETUP(asrc, m0 + row)
  f32x4 acc[4][2] = {};
  const int NT = DM / 32;   // 64
#pragma unroll
  for (int q = 0; q < 4; ++q) {
    A_STAGE(asrc, lA[q], q * 32)
    B_STAGE(bsrc, lB[q], q * 32, HSH)
  }
#pragma unroll 1
  for (int t = 0; t < NT - 4; t += 4) {
    MM_STEP(0, t + 4, HSH)
    MM_STEP(1, t + 5, HSH)
    MM_STEP(2, t + 6, HSH)
    MM_STEP(3, t + 7, HSH)
  }
  MM_PEEL(0, 12) MM_PEEL(1, 8) MM_PEEL(2, 4) MM_PEEL(3, 0)
#pragma unroll
  for (int mf = 0; mf < 4; ++mf)
#pragma unroll
    for (int nf = 0; nf < 2; ++nf)
#pragma unroll
      for (int r = 0; r < 4; ++r) {
        int row = m0 + wm + mf * 16 + (lane >> 4) * 4 + r;
        int col = n0 + wn + nf * 16 + (lane & 15);
        hdst[(size_t)row * (NSH * HSH) + s * HSH + col] = f2bf(acc[mf][nf][r]);
      }
}

// ---------------------------------------------------------------- shared swiglu
__global__ __launch_bounds__(256) void k_swiglu_s(const unsigned short* __restrict__ hsg,
    const unsigned short* __restrict__ hsu, unsigned short* __restrict__ hs) {
  int gid = blockIdx.x * 256 + threadIdx.x;
  size_t o = (size_t)gid * 8;
  short8 g8 = *(const short8*)(hsg + o);
  short8 u8 = *(const short8*)(hsu + o);
  short8 r;
#pragma unroll
  for (int j = 0; j < 8; ++j) {
    union { unsigned u; float f; } gg, uu;
    gg.u = ((unsigned)(unsigned short)g8[j]) << 16;
    uu.u = ((unsigned)(unsigned short)u8[j]) << 16;
    r[j] = f2bf(silu_mul(gg.f, uu.f));
  }
  *(short8*)(hs + o) = r;
}

// ---------------------------------------------------------------- shared down (writes out)
// grid 512 = (mb 16) x (nb 32), K = 4096
__global__ __launch_bounds__(256, 2) void k_sd4(const unsigned short* __restrict__ hs,
    const float* __restrict__ Sd, float* __restrict__ out) {
  int bid = blockIdx.x;
  int nb = bid & 31, mb = bid >> 5;
  int n0 = nb * 64, m0 = mb * 128;
  __shared__ unsigned short lA[4][128 * 32];
  __shared__ float lB[4][32 * 64];
  int tid = threadIdx.x, lane = tid & 63, wv = tid >> 6;
  int wm = (wv >> 1) * 64, wn = (wv & 1) * 32;
  const unsigned short* Abase = hs; const int lda = NSH * HSH;
  B_SETUP(bsrc, Sd, DM)
  A_SETUP(asrc, m0 + row)
  f32x4 acc[4][2] = {};
  const int NT = (NSH * HSH) / 32;  // 128
#pragma unroll
  for (int q = 0; q < 4; ++q) {
    A_STAGE(asrc, lA[q], q * 32)
    B_STAGE(bsrc, lB[q], q * 32, DM)
  }
#pragma unroll 1
  for (int t = 0; t < NT - 4; t += 4) {
    MM_STEP(0, t + 4, DM)
    MM_STEP(1, t + 5, DM)
    MM_STEP(2, t + 6, DM)
    MM_STEP(3, t + 7, DM)
  }
  MM_PEEL(0, 12) MM_PEEL(1, 8) MM_PEEL(2, 4) MM_PEEL(3, 0)
#pragma unroll
  for (int mf = 0; mf < 4; ++mf)
#pragma unroll
    for (int nf = 0; nf < 2; ++nf)
#pragma unroll
      for (int r = 0; r < 4; ++r) {
        int row = m0 + wm + mf * 16 + (lane >> 4) * 4 + r;
        int col = n0 + wn + nf * 16 + (lane & 15);
        out[(size_t)row * DM + col] = acc[mf][nf][r];
      }
}

// ---------------------------------------------------------------- expert down (atomic add)
// grid 2048 = (e 64) x (nb 32), e XCD-colocated
__global__ __launch_bounds__(256, 2) void k_downE(const unsigned short* __restrict__ hws,
    const float* __restrict__ Wd, const int* __restrict__ cnt, const int* __restrict__ offs,
    const int* __restrict__ lists, const float* __restrict__ wlist,
    float* __restrict__ out) {
  int bid = blockIdx.x;
  int e  = ((bid & 7) << 3) | ((bid >> 3) & 7);
  int nb = bid >> 6;
  int n0 = nb * 64;
  int ne = min(cnt[e], CAPC);
  if (ne == 0) return;
  const float* B = Wd + (size_t)e * HEXP * DM;
  __shared__ unsigned short lA[4][128 * 32];
  __shared__ float lB[4][32 * 64];
  int tid = threadIdx.x, lane = tid & 63, wv = tid >> 6;
  int wm = (wv >> 1) * 64, wn = (wv & 1) * 32;
  const unsigned short* Abase = hws + (size_t)offs[e] * HEXP; const int lda = HEXP;
  B_SETUP(bsrc, B, DM)
  const int NT = HEXP / 32;   // 16
  for (int m0 = 0; m0 < ne; m0 += 128) {
    A_SETUP(asrc, min(m0 + row, ne - 1))
    f32x4 acc[4][2] = {};
#pragma unroll
    for (int q = 0; q < 4; ++q) {
      A_STAGE(asrc, lA[q], q * 32)
      B_STAGE(bsrc, lB[q], q * 32, DM)
    }
#pragma unroll 1
    for (int t = 0; t < NT - 4; t += 4) {
      MM_STEP(0, t + 4, DM)
      MM_STEP(1, t + 5, DM)
      MM_STEP(2, t + 6, DM)
      MM_STEP(3, t + 7, DM)
    }
    MM_PEEL(0, 12) MM_PEEL(1, 8) MM_PEEL(2, 4) MM_PEEL(3, 0)
    BARX();
#pragma unroll
    for (int mf = 0; mf < 4; ++mf)
#pragma unroll
      for (int r = 0; r < 4; ++r) {
        int rl = m0 + wm + mf * 16 + (lane >> 4) * 4 + r;
        if (rl < ne) {
          int tok  = lists[e * CAPC + rl];
          float w  = wlist[e * CAPC + rl];
#pragma unroll
          for (int nf = 0; nf < 2; ++nf) {
            int col = n0 + wn + nf * 16 + (lane & 15);
            atomicAdd(out + (size_t)tok * DM + col, acc[mf][nf][r] * w);
          }
        }
      }
  }
}

// ---------------------------------------------------------------- launch
extern "C" void kernel_launch(void* const* d_in, const int* in_sizes, int n_in,
                              void* d_out, int out_size, void* d_ws, size_t ws_size,
                              hipStream_t stream) {
  const float* x    = (const float*)d_in[0];
  const float* Wr   = (const float*)d_in[1];
  const float* bias = (const float*)d_in[2];
  const float* Wg   = (const float*)d_in[3];
  const float* Wu   = (const float*)d_in[4];
  const float* Wd   = (const float*)d_in[5];
  const float* Sg   = (const float*)d_in[6];
  const float* Su   = (const float*)d_in[7];
  const float* Sd   = (const float*)d_in[8];
  float* out = (float*)d_out;
  char* ws = (char*)d_ws;

  const size_t off_cnt   = 0;
  const size_t off_offs  = 256;
  const size_t off_lists = 1024;
  const size_t off_wlist = off_lists + (size_t)NEXP * CAPC * 4;
  const size_t off_xbf   = off_wlist + (size_t)NEXP * CAPC * 4;
  const size_t off_hs    = off_xbf + (size_t)N_TOK * DM * 2;
  const size_t off_hws   = off_hs + (size_t)N_TOK * NSH * HSH * 2;
  const size_t off_hg    = off_hws + (size_t)N_TOK * TOPK * HEXP * 2;
  const size_t off_hu    = off_hg + (size_t)N_TOK * TOPK * HEXP * 2;
  const size_t off_hsg   = off_hu + (size_t)N_TOK * TOPK * HEXP * 2;
  const size_t off_hsu   = off_hsg + (size_t)N_TOK * NSH * HSH * 2;
  const size_t req       = off_hsu + (size_t)N_TOK * NSH * HSH * 2;
  if (ws_size < req) return;

  int* cnt            = (int*)(ws + off_cnt);
  int* offs           = (int*)(ws + off_offs);
  int* lists          = (int*)(ws + off_lists);
  float* wlist        = (float*)(ws + off_wlist);
  unsigned short* xbf = (unsigned short*)(ws + off_xbf);
  unsigned short* hs  = (unsigned short*)(ws + off_hs);
  unsigned short* hws = (unsigned short*)(ws + off_hws);
  unsigned short* hg  = (unsigned short*)(ws + off_hg);
  unsigned short* hu  = (unsigned short*)(ws + off_hu);
  unsigned short* hsg = (unsigned short*)(ws + off_hsg);
  unsigned short* hsu = (unsigned short*)(ws + off_hsu);

  hipMemsetAsync(cnt, 0, NEXP * sizeof(int), stream);
  k_convert<<<(N_TOK * DM) / (256 * 8), 256, 0, stream>>>(x, xbf);
  k_router<<<N_TOK / RTB, 256, 0, stream>>>(x, Wr, bias, cnt, lists, wlist);
  k_offs<<<1, 64, 0, stream>>>(cnt, offs);

  k_mmE<<<1024, 256, 0, stream>>>(xbf, Wg, Wu, cnt, offs, lists, hg, hu);
  k_swiglu_e<<<(N_TOK * TOPK * HEXP / 8) / 256, 256, 0, stream>>>(hg, hu, offs, hws);

  k_mmS<<<2048, 256, 0, stream>>>(xbf, Sg, Su, hsg, hsu);
  k_swiglu_s<<<(N_TOK * NSH * HSH / 8) / 256, 256, 0, stream>>>(hsg, hsu, hs);

  k_sd4<<<512, 256, 0, stream>>>(hs, Sd, out);
  k_downE<<<2048, 256, 0, stream>>>(hws, Wd, cnt, offs, lists, wlist, out);
}